// Round 2
// baseline (206.319 us; speedup 1.0000x reference)
//
#include <hip/hip_runtime.h>
#include <stdint.h>

// SAGAN self-attention, MI355X gfx950.
// B=8, C=256, CK=32, N=4096. fp32 in/out, bf16 MFMA internally.

typedef __bf16 bf16;
typedef __bf16 bf16x8 __attribute__((ext_vector_type(8)));
typedef float  f32x16 __attribute__((ext_vector_type(16)));

#define BATCH 8
#define CC    256
#define CKK   32
#define NN    4096
#define LOG2E 1.4426950408889634f

__device__ __forceinline__ f32x16 zero16() {
  f32x16 z;
#pragma unroll
  for (int i = 0; i < 16; ++i) z[i] = 0.0f;
  return z;
}

__device__ __forceinline__ unsigned pack2(float lo, float hi) {
  unsigned short a = __builtin_bit_cast(unsigned short, (bf16)lo);
  unsigned short b = __builtin_bit_cast(unsigned short, (bf16)hi);
  return (unsigned)a | ((unsigned)b << 16);
}

__device__ __forceinline__ f32x16 mfma32(bf16x8 a, bf16x8 b, f32x16 c) {
  return __builtin_amdgcn_mfma_f32_32x32x16_bf16(a, b, c, 0, 0, 0);
}

#define GLDS16(srcp, dstp)                                                         \
  __builtin_amdgcn_global_load_lds(                                               \
      (const __attribute__((address_space(1))) void*)(srcp),                      \
      (__attribute__((address_space(3))) void*)(dstp), 16, 0, 0)

// ---------------- kernel 0a: x f32 [B][C][N] -> xT bf16 [B][N][C] ----------------
__global__ __launch_bounds__(256) void k_transpose(const float* __restrict__ x,
                                                   bf16* __restrict__ xT) {
  __shared__ float tile[64][65];
  const int n0 = blockIdx.x * 64;
  const int c0 = blockIdx.y * 64;
  const int b  = blockIdx.z;
  const int t = threadIdx.x;
  const int tn = t & 63, trow = t >> 6;
#pragma unroll
  for (int i = 0; i < 16; ++i) {
    int c = trow + i * 4;
    tile[c][tn] = x[((size_t)(b * CC + c0 + c)) * NN + n0 + tn];
  }
  __syncthreads();
#pragma unroll
  for (int i = 0; i < 16; ++i) {
    int n = trow + i * 4;
    xT[((size_t)(b * NN + n0 + n)) * CC + c0 + tn] = (bf16)tile[tn][n];
  }
}

// ---------------- kernel 0b: weight pack ----------------
// Wcat bf16 [320][256]: rows 0..31 = Wf, 32..63 = Wg*log2e, 64..319 = Wh.
// bcat f32 [320] likewise (bg scaled by log2e).
__global__ __launch_bounds__(64) void k_wprep(const float* __restrict__ Wf, const float* __restrict__ bfv,
                                              const float* __restrict__ Wg, const float* __restrict__ bg,
                                              const float* __restrict__ Wh, const float* __restrict__ bh,
                                              bf16* __restrict__ Wcat, float* __restrict__ bcat) {
  const int ko = blockIdx.x;  // 0..319
  const int t = threadIdx.x;
  const float* src;
  float scale = 1.0f;
  if (ko < 32) src = Wf + (size_t)ko * CC;
  else if (ko < 64) { src = Wg + (size_t)(ko - 32) * CC; scale = LOG2E; }
  else src = Wh + (size_t)(ko - 64) * CC;
#pragma unroll
  for (int i = 0; i < 4; ++i)
    Wcat[(size_t)ko * CC + t + i * 64] = (bf16)(src[t + i * 64] * scale);
  if (ko == 0) {
    for (int i = t; i < 320; i += 64) {
      float v = (i < 32) ? bfv[i] : (i < 64) ? bg[i - 32] * LOG2E : bh[i - 64];
      bcat[i] = v;
    }
  }
}

// ---------------- kernel 1: projections (MFMA GEMM 320x256 @ x) ----------------
// fxT/gxT: bf16 [B][N][32]  (row-per-pixel, K-major for attention frag loads)
// hx:      bf16 [B][C][N]
__global__ __launch_bounds__(256, 1) void k_proj(const bf16* __restrict__ xT,
                                                 const bf16* __restrict__ Wcat,
                                                 const float* __restrict__ bcat,
                                                 bf16* __restrict__ fxT, bf16* __restrict__ gxT,
                                                 bf16* __restrict__ hx) {
  const int d = blockIdx.x;
  const int b = d & 7, nb = d >> 3;          // batch -> XCD alignment
  const int t = threadIdx.x;
  const int w = t >> 6, ln = t & 63, ln31 = ln & 31, h = ln >> 5;
  const int n = nb * 128 + w * 32 + ln31;    // this lane's output column

  f32x16 acc[10];
#pragma unroll
  for (int mt = 0; mt < 10; ++mt) acc[mt] = zero16();

  const bf16* xrow = xT + ((size_t)(b * NN + n)) * CC;
#pragma unroll
  for (int ks = 0; ks < 16; ++ks) {
    bf16x8 bfrag = *(const bf16x8*)(xrow + ks * 16 + h * 8);  // B[k=c][n]
#pragma unroll
    for (int mt = 0; mt < 10; ++mt) {
      bf16x8 afrag = *(const bf16x8*)(Wcat + (size_t)(mt * 32 + ln31) * CC + ks * 16 + h * 8);
      acc[mt] = mfma32(afrag, bfrag, acc[mt]);
    }
  }

#pragma unroll
  for (int mt = 0; mt < 10; ++mt) {
#pragma unroll
    for (int q = 0; q < 4; ++q) {
      const int ko0 = mt * 32 + 8 * q + 4 * h;  // rows ko0..ko0+3
      float v0 = acc[mt][4 * q + 0] + bcat[ko0 + 0];
      float v1 = acc[mt][4 * q + 1] + bcat[ko0 + 1];
      float v2 = acc[mt][4 * q + 2] + bcat[ko0 + 2];
      float v3 = acc[mt][4 * q + 3] + bcat[ko0 + 3];
      if (mt < 2) {
        bf16* dst = (mt == 0 ? fxT : gxT) + ((size_t)(b * NN + n)) * CKK + (8 * q + 4 * h);
        uint2 pv;
        pv.x = pack2(v0, v1);
        pv.y = pack2(v2, v3);
        *(uint2*)dst = pv;
      } else {
        const int c = ko0 - 64;
        hx[((size_t)(b * CC + c + 0)) * NN + n] = (bf16)v0;
        hx[((size_t)(b * CC + c + 1)) * NN + n] = (bf16)v1;
        hx[((size_t)(b * CC + c + 2)) * NN + n] = (bf16)v2;
        hx[((size_t)(b * CC + c + 3)) * NN + n] = (bf16)v3;
      }
    }
  }
}

// ---------------- kernel 2: flash attention ----------------
// Grid 256 (b = blk&7 -> XCD-local V). Block = 4 waves, 32 queries each.
// Per 64-key block: S = K·Q (2x2 mfma), online softmax (log2 domain, defer-max),
// in-register P transpose via shfl_xor(32), O += V·P (8x4 mfma).
__global__ __launch_bounds__(256, 1) void k_attn(const bf16* __restrict__ fxT,
                                                 const bf16* __restrict__ gxT,
                                                 const bf16* __restrict__ hx,
                                                 const float* __restrict__ x,
                                                 const float* __restrict__ gammap,
                                                 float* __restrict__ out) {
  __shared__ __align__(16) bf16 vbuf[2][16384];  // 2 x 32KB V tiles [256 c][64 i], chunk-swizzled
  const int d = blockIdx.x;
  const int b = d & 7, jb = d >> 3;
  const int t = threadIdx.x;
  const int w = t >> 6, ln = t & 63, ln31 = ln & 31, h = ln >> 5;
  const int j = jb * 128 + w * 32 + ln31;

  const bf16* fxb = fxT + (size_t)b * NN * CKK;
  const bf16* hxb = hx + (size_t)b * CC * NN;

  const bf16* qrow = gxT + ((size_t)b * NN + j) * CKK;
  bf16x8 qf0 = *(const bf16x8*)(qrow + h * 8);        // ck 0..15 half (per-lane)
  bf16x8 qf1 = *(const bf16x8*)(qrow + 16 + h * 8);   // ck 16..31

  f32x16 oacc[8];
#pragma unroll
  for (int ct = 0; ct < 8; ++ct) oacc[ct] = zero16();
  float m_ref = -__builtin_inff();
  float l_run = 0.0f;

  // per-lane swizzled V-frag offsets (elements): row=ln31, phys chunk=(2kk+h)^(ln31&7)
  int voff[4];
#pragma unroll
  for (int kk = 0; kk < 4; ++kk)
    voff[kk] = ln31 * 64 + (((2 * kk + h) ^ (ln31 & 7)) * 8);

  // prologue: stage key-block 0 (pre-swizzled global source, linear LDS dest)
#pragma unroll
  for (int q = 0; q < 8; ++q) {
    int f = q * 256 + t;
    int row = f >> 3;
    int lc = (f & 7) ^ (row & 7);
    const bf16* src = hxb + (size_t)row * NN + lc * 8;
    bf16* dst = &vbuf[0][(q * 256 + (t & 192)) * 8];
    GLDS16(src, dst);
  }
  asm volatile("s_waitcnt vmcnt(0)" ::: "memory");
  __syncthreads();

  for (int kb = 0; kb < 64; ++kb) {
    const int i0 = kb * 64;

    // K fragments first (oldest loads -> compiler waits leave staging outstanding)
    const bf16* kr0 = fxb + ((size_t)(i0 + ln31)) * CKK;
    const bf16* kr1 = fxb + ((size_t)(i0 + 32 + ln31)) * CKK;
    bf16x8 kf00 = *(const bf16x8*)(kr0 + h * 8);
    bf16x8 kf01 = *(const bf16x8*)(kr0 + 16 + h * 8);
    bf16x8 kf10 = *(const bf16x8*)(kr1 + h * 8);
    bf16x8 kf11 = *(const bf16x8*)(kr1 + 16 + h * 8);

    // async-stage next key-block into the other buffer
    if (kb < 63) {
      bf16* nbuf = &vbuf[(kb + 1) & 1][0];
#pragma unroll
      for (int q = 0; q < 8; ++q) {
        int f = q * 256 + t;
        int row = f >> 3;
        int lc = (f & 7) ^ (row & 7);
        const bf16* src = hxb + (size_t)row * NN + (i0 + 64) + lc * 8;
        bf16* dst = nbuf + (q * 256 + (t & 192)) * 8;
        GLDS16(src, dst);
      }
    }
    const bf16* vb = &vbuf[kb & 1][0];

    // S[i,j] = <fx_i, gx_j> (already in log2 domain via pre-scaled Wg)
    f32x16 s0 = zero16(), s1 = zero16();
    s0 = mfma32(kf00, qf0, s0);
    s0 = mfma32(kf01, qf1, s0);
    s1 = mfma32(kf10, qf0, s1);
    s1 = mfma32(kf11, qf1, s1);

    // block max over all 64 keys for this j (4 h-halves: lane l and l^32 share j)
    float smax = -__builtin_inff();
#pragma unroll
    for (int r = 0; r < 16; ++r) {
      smax = fmaxf(smax, s0[r]);
      smax = fmaxf(smax, s1[r]);
    }
    smax = fmaxf(smax, __shfl_xor(smax, 32));

    // defer-max rescale (THR=8 in exp2 domain -> P <= 256, bf16-safe)
    bool need = smax > m_ref + 8.0f;
    if (__any(need)) {
      float rr = need ? __builtin_exp2f(m_ref - smax) : 1.0f;
      if (need) m_ref = smax;
      l_run *= rr;
#pragma unroll
      for (int ct = 0; ct < 8; ++ct)
#pragma unroll
        for (int r = 0; r < 16; ++r) oacc[ct][r] *= rr;
    }

    // P = exp2(S - m_ref), pack to bf16 pairs
    float lsum = 0.0f;
    unsigned pk0[4][2], pk1[4][2];
#pragma unroll
    for (int q = 0; q < 4; ++q) {
#pragma unroll
      for (int wi = 0; wi < 2; ++wi) {
        float a0 = __builtin_exp2f(s0[4 * q + 2 * wi] - m_ref);
        float a1 = __builtin_exp2f(s0[4 * q + 2 * wi + 1] - m_ref);
        float b0 = __builtin_exp2f(s1[4 * q + 2 * wi] - m_ref);
        float b1 = __builtin_exp2f(s1[4 * q + 2 * wi + 1] - m_ref);
        lsum += (a0 + a1) + (b0 + b1);
        pk0[q][wi] = pack2(a0, a1);
        pk1[q][wi] = pack2(b0, b1);
      }
    }
    lsum += __shfl_xor(lsum, 32);
    l_run += lsum;

    // in-register transpose: S-frag (rows 4-interleaved) -> PV B-frag (rows 8-contig).
    // Only lane<->lane^32 exchange needed; 1 shfl + 3 selects per word-pair.
    bf16x8 pf[4];
#pragma unroll
    for (int kk = 0; kk < 4; ++kk) {
      const int qb = 2 * (kk & 1);
      union { unsigned u[4]; bf16x8 v; } pu;
#pragma unroll
      for (int wi = 0; wi < 2; ++wi) {
        unsigned a  = (kk < 2) ? pk0[qb][wi]     : pk1[qb][wi];
        unsigned bv = (kk < 2) ? pk0[qb + 1][wi] : pk1[qb + 1][wi];
        unsigned sv = h ? a : bv;
        unsigned rv = (unsigned)__shfl_xor((int)sv, 32);
        pu.u[wi]     = h ? rv : a;
        pu.u[2 + wi] = h ? bv : rv;
      }
      pf[kk] = pu.v;
    }

    // O[c,j] += V[c,i] * P[i,j]
#pragma unroll
    for (int ct = 0; ct < 8; ++ct) {
      const bf16* vrow = vb + ct * 2048;
      oacc[ct] = mfma32(*(const bf16x8*)(vrow + voff[0]), pf[0], oacc[ct]);
      oacc[ct] = mfma32(*(const bf16x8*)(vrow + voff[1]), pf[1], oacc[ct]);
      oacc[ct] = mfma32(*(const bf16x8*)(vrow + voff[2]), pf[2], oacc[ct]);
      oacc[ct] = mfma32(*(const bf16x8*)(vrow + voff[3]), pf[3], oacc[ct]);
    }

    asm volatile("s_waitcnt vmcnt(0)" ::: "memory");
    __syncthreads();
  }

  // epilogue: out = gamma * O/l + x
  const float ginv = gammap[0] / l_run;
  const float* xb = x + (size_t)b * CC * NN;
  float* ob = out + (size_t)b * CC * NN;
#pragma unroll
  for (int ct = 0; ct < 8; ++ct) {
#pragma unroll
    for (int r = 0; r < 16; ++r) {
      int c = ct * 32 + (r & 3) + 8 * (r >> 2) + 4 * h;
      size_t idx = (size_t)c * NN + j;
      ob[idx] = fmaf(ginv, oacc[ct][r], xb[idx]);
    }
  }
}

extern "C" void kernel_launch(void* const* d_in, const int* in_sizes, int n_in,
                              void* d_out, int out_size, void* d_ws, size_t ws_size,
                              hipStream_t stream) {
  const float* x     = (const float*)d_in[0];
  const float* Wf    = (const float*)d_in[1];
  const float* bfv   = (const float*)d_in[2];
  const float* Wg    = (const float*)d_in[3];
  const float* bg    = (const float*)d_in[4];
  const float* Wh    = (const float*)d_in[5];
  const float* bh    = (const float*)d_in[6];
  const float* gamma = (const float*)d_in[7];
  float* out = (float*)d_out;

  // workspace layout (~21.2 MB); xT lives in d_out (33.5 MB) since out is written last.
  char* ws = (char*)d_ws;
  bf16* fxT  = (bf16*)(ws);                      //  2 MB
  bf16* gxT  = (bf16*)(ws + 2097152);            //  2 MB
  bf16* hx   = (bf16*)(ws + 4194304);            // 16.8 MB
  bf16* Wcat = (bf16*)(ws + 20971520);           // 160 KB
  float* bcat = (float*)(ws + 21135360);         // 1.25 KB
  bf16* xT = (bf16*)d_out;                       // 16.8 MB scratch, dead before k_attn writes

  k_transpose<<<dim3(64, 4, 8), 256, 0, stream>>>(x, xT);
  k_wprep<<<dim3(320), 64, 0, stream>>>(Wf, bfv, Wg, bg, Wh, bh, Wcat, bcat);
  k_proj<<<dim3(256), 256, 0, stream>>>(xT, Wcat, bcat, fxT, gxT, hx);
  k_attn<<<dim3(256), 256, 0, stream>>>(fxT, gxT, hx, x, gamma, out);
}

// Round 3
// 161.762 us; speedup vs baseline: 1.2754x; 1.2754x over previous
//
#include <hip/hip_runtime.h>
#include <stdint.h>

// SAGAN self-attention, MI355X gfx950.
// B=8, C=256, CK=32, N=4096. fp32 in/out, bf16 MFMA internally.

typedef __bf16 bf16;
typedef __bf16 bf16x8 __attribute__((ext_vector_type(8)));
typedef float  f32x16 __attribute__((ext_vector_type(16)));
typedef float  f32x4  __attribute__((ext_vector_type(4)));

#define BATCH 8
#define CC    256
#define CKK   32
#define NN    4096
#define LOG2E 1.4426950408889634f

__device__ __forceinline__ f32x16 zero16() {
  f32x16 z;
#pragma unroll
  for (int i = 0; i < 16; ++i) z[i] = 0.0f;
  return z;
}

__device__ __forceinline__ unsigned pack2(float lo, float hi) {
  unsigned short a = __builtin_bit_cast(unsigned short, (bf16)lo);
  unsigned short b = __builtin_bit_cast(unsigned short, (bf16)hi);
  return (unsigned)a | ((unsigned)b << 16);
}

__device__ __forceinline__ f32x16 mfma32(bf16x8 a, bf16x8 b, f32x16 c) {
  return __builtin_amdgcn_mfma_f32_32x32x16_bf16(a, b, c, 0, 0, 0);
}

#define GLDS16(srcp, dstp)                                                         \
  __builtin_amdgcn_global_load_lds(                                               \
      (const __attribute__((address_space(1))) void*)(srcp),                      \
      (__attribute__((address_space(3))) void*)(dstp), 16, 0, 0)

// ---------------- kernel 0a: x f32 [B][C][N] -> xT bf16 [B][N][C] ----------------
__global__ __launch_bounds__(256) void k_transpose(const float* __restrict__ x,
                                                   bf16* __restrict__ xT) {
  __shared__ float tile[64][65];
  const int n0 = blockIdx.x * 64;
  const int c0 = blockIdx.y * 64;
  const int b  = blockIdx.z;
  const int t = threadIdx.x;
  const int tn = t & 63, trow = t >> 6;
#pragma unroll
  for (int i = 0; i < 16; ++i) {
    int c = trow + i * 4;
    tile[c][tn] = x[((size_t)(b * CC + c0 + c)) * NN + n0 + tn];
  }
  __syncthreads();
#pragma unroll
  for (int i = 0; i < 16; ++i) {
    int n = trow + i * 4;
    xT[((size_t)(b * NN + n0 + n)) * CC + c0 + tn] = (bf16)tile[tn][n];
  }
}

// ---------------- kernel 0b: weight pack ----------------
// Wcat bf16 [320][256]: rows 0..31 = Wf, 32..63 = Wg*log2e, 64..319 = Wh.
// bcat f32 [320] likewise (bg scaled by log2e).
__global__ __launch_bounds__(64) void k_wprep(const float* __restrict__ Wf, const float* __restrict__ bfv,
                                              const float* __restrict__ Wg, const float* __restrict__ bg,
                                              const float* __restrict__ Wh, const float* __restrict__ bh,
                                              bf16* __restrict__ Wcat, float* __restrict__ bcat) {
  const int ko = blockIdx.x;  // 0..319
  const int t = threadIdx.x;
  const float* src;
  float scale = 1.0f;
  if (ko < 32) src = Wf + (size_t)ko * CC;
  else if (ko < 64) { src = Wg + (size_t)(ko - 32) * CC; scale = LOG2E; }
  else src = Wh + (size_t)(ko - 64) * CC;
#pragma unroll
  for (int i = 0; i < 4; ++i)
    Wcat[(size_t)ko * CC + t + i * 64] = (bf16)(src[t + i * 64] * scale);
  if (ko == 0) {
    for (int i = t; i < 320; i += 64) {
      float v = (i < 32) ? bfv[i] : (i < 64) ? bg[i - 32] * LOG2E : bh[i - 64];
      bcat[i] = v;
    }
  }
}

// ---------------- kernel 1: projections (MFMA GEMM 320x256 @ x) ----------------
// fxT/gxT: bf16 [B][N][32]  (row-per-pixel, K-major for attention frag loads)
// hx:      bf16 [B][C][N]
__global__ __launch_bounds__(256, 1) void k_proj(const bf16* __restrict__ xT,
                                                 const bf16* __restrict__ Wcat,
                                                 const float* __restrict__ bcat,
                                                 bf16* __restrict__ fxT, bf16* __restrict__ gxT,
                                                 bf16* __restrict__ hx) {
  const int d = blockIdx.x;
  const int b = d & 7, nb = d >> 3;          // batch -> XCD alignment
  const int t = threadIdx.x;
  const int w = t >> 6, ln = t & 63, ln31 = ln & 31, h = ln >> 5;
  const int n = nb * 128 + w * 32 + ln31;    // this lane's output column

  f32x16 acc[10];
#pragma unroll
  for (int mt = 0; mt < 10; ++mt) acc[mt] = zero16();

  const bf16* xrow = xT + ((size_t)(b * NN + n)) * CC;
#pragma unroll
  for (int ks = 0; ks < 16; ++ks) {
    bf16x8 bfrag = *(const bf16x8*)(xrow + ks * 16 + h * 8);  // B[k=c][n]
#pragma unroll
    for (int mt = 0; mt < 10; ++mt) {
      bf16x8 afrag = *(const bf16x8*)(Wcat + (size_t)(mt * 32 + ln31) * CC + ks * 16 + h * 8);
      acc[mt] = mfma32(afrag, bfrag, acc[mt]);
    }
  }

#pragma unroll
  for (int mt = 0; mt < 10; ++mt) {
#pragma unroll
    for (int q = 0; q < 4; ++q) {
      const int ko0 = mt * 32 + 8 * q + 4 * h;  // rows ko0..ko0+3
      float v0 = acc[mt][4 * q + 0] + bcat[ko0 + 0];
      float v1 = acc[mt][4 * q + 1] + bcat[ko0 + 1];
      float v2 = acc[mt][4 * q + 2] + bcat[ko0 + 2];
      float v3 = acc[mt][4 * q + 3] + bcat[ko0 + 3];
      if (mt < 2) {
        bf16* dst = (mt == 0 ? fxT : gxT) + ((size_t)(b * NN + n)) * CKK + (8 * q + 4 * h);
        uint2 pv;
        pv.x = pack2(v0, v1);
        pv.y = pack2(v2, v3);
        *(uint2*)dst = pv;
      } else {
        const int c = ko0 - 64;
        hx[((size_t)(b * CC + c + 0)) * NN + n] = (bf16)v0;
        hx[((size_t)(b * CC + c + 1)) * NN + n] = (bf16)v1;
        hx[((size_t)(b * CC + c + 2)) * NN + n] = (bf16)v2;
        hx[((size_t)(b * CC + c + 3)) * NN + n] = (bf16)v3;
      }
    }
  }
}

// ---------------- kernel 2: flash attention, key-split 8-wave ----------------
// Grid 256 (b = blk&7 -> XCD-local V). Block = 512 threads = 2 key-groups x 4 waves.
// Group g handles keys [g*2048, g*2048+2048) over 32 iterations with its own
// double-buffered 2x32KB LDS V area (128KB dynamic total). Joint barrier amortizes
// the staging-drain latency over 2x compute; 2 waves/SIMD give TLP during stalls.
// End: in-block merge of the two (O, m, l) partials through the dead V buffers.
__global__ __launch_bounds__(512, 2) void k_attn(const bf16* __restrict__ fxT,
                                                 const bf16* __restrict__ gxT,
                                                 const bf16* __restrict__ hx,
                                                 const float* __restrict__ x,
                                                 const float* __restrict__ gammap,
                                                 float* __restrict__ out) {
  extern __shared__ __align__(16) char smem[];   // 133120 B: 4x32KB V / merge obuf
  __shared__ float msh[128], lsh[128];
  const int d = blockIdx.x;
  const int b = d & 7, jb = d >> 3;
  const int t = threadIdx.x;
  const int g = t >> 8;                 // key-half group (waves 0-3 / 4-7)
  const int tg = t & 255;               // thread-in-group
  const int wg = tg >> 6;               // wave-in-group
  const int ln = t & 63, ln31 = ln & 31, h = ln >> 5;
  const int j = jb * 128 + wg * 32 + ln31;
  const int kbase = g * 2048;

  const bf16* fxb = fxT + (size_t)b * NN * CKK;
  const bf16* hxb = hx + (size_t)b * CC * NN;

  const bf16* qrow = gxT + ((size_t)b * NN + j) * CKK;
  bf16x8 qf0 = *(const bf16x8*)(qrow + h * 8);        // ck 0..15 half (per-lane)
  bf16x8 qf1 = *(const bf16x8*)(qrow + 16 + h * 8);   // ck 16..31

  f32x16 oacc[8];
#pragma unroll
  for (int ct = 0; ct < 8; ++ct) oacc[ct] = zero16();
  float m_ref = -__builtin_inff();
  float l_run = 0.0f;

  // per-lane swizzled V-frag offsets (elements): row=ln31, phys chunk=(2kk+h)^(ln31&7)
  int voff[4];
#pragma unroll
  for (int kk = 0; kk < 4; ++kk)
    voff[kk] = ln31 * 64 + (((2 * kk + h) ^ (ln31 & 7)) * 8);

  // prologue: stage this group's key-block 0 (pre-swizzled global src, linear LDS dst)
  {
    bf16* vbase = (bf16*)(smem + (size_t)(g * 2) * 32768);
#pragma unroll
    for (int q = 0; q < 8; ++q) {
      int f = q * 256 + tg;
      int row = f >> 3;
      int lc = (f & 7) ^ (row & 7);
      const bf16* src = hxb + (size_t)row * NN + kbase + lc * 8;
      bf16* dst = vbase + (q * 256 + (tg & 192)) * 8;
      GLDS16(src, dst);
    }
  }
  asm volatile("s_waitcnt vmcnt(0)" ::: "memory");
  __syncthreads();

  for (int kb = 0; kb < 32; ++kb) {
    const int i0 = kbase + kb * 64;

    // K fragments first (oldest loads -> compiler waits leave staging outstanding)
    const bf16* kr0 = fxb + ((size_t)(i0 + ln31)) * CKK;
    const bf16* kr1 = fxb + ((size_t)(i0 + 32 + ln31)) * CKK;
    bf16x8 kf00 = *(const bf16x8*)(kr0 + h * 8);
    bf16x8 kf01 = *(const bf16x8*)(kr0 + 16 + h * 8);
    bf16x8 kf10 = *(const bf16x8*)(kr1 + h * 8);
    bf16x8 kf11 = *(const bf16x8*)(kr1 + 16 + h * 8);

    // async-stage this group's next key-block into its other buffer
    if (kb < 31) {
      bf16* nbuf = (bf16*)(smem + (size_t)(g * 2 + ((kb + 1) & 1)) * 32768);
#pragma unroll
      for (int q = 0; q < 8; ++q) {
        int f = q * 256 + tg;
        int row = f >> 3;
        int lc = (f & 7) ^ (row & 7);
        const bf16* src = hxb + (size_t)row * NN + (i0 + 64) + lc * 8;
        bf16* dst = nbuf + (q * 256 + (tg & 192)) * 8;
        GLDS16(src, dst);
      }
    }
    const bf16* vb = (const bf16*)(smem + (size_t)(g * 2 + (kb & 1)) * 32768);

    // S[i,j] = <fx_i, gx_j> (already in log2 domain via pre-scaled Wg)
    f32x16 s0 = zero16(), s1 = zero16();
    s0 = mfma32(kf00, qf0, s0);
    s0 = mfma32(kf01, qf1, s0);
    s1 = mfma32(kf10, qf0, s1);
    s1 = mfma32(kf11, qf1, s1);

    // block max over all 64 keys for this j — tree reduce (short dep chain)
    float tm[16];
#pragma unroll
    for (int r = 0; r < 16; ++r) tm[r] = fmaxf(s0[r], s1[r]);
#pragma unroll
    for (int st = 8; st > 0; st >>= 1)
#pragma unroll
      for (int r = 0; r < 8; ++r)
        if (r < st) tm[r] = fmaxf(tm[r], tm[r + st]);
    float smax = fmaxf(tm[0], __shfl_xor(tm[0], 32));

    // defer-max rescale (THR=8 in exp2 domain -> P <= 256, bf16-safe)
    bool need = smax > m_ref + 8.0f;
    if (__any(need)) {
      float rr = need ? __builtin_exp2f(m_ref - smax) : 1.0f;
      if (need) m_ref = smax;
      l_run *= rr;
#pragma unroll
      for (int ct = 0; ct < 8; ++ct)
#pragma unroll
        for (int r = 0; r < 16; ++r) oacc[ct][r] *= rr;
    }

    // P = exp2(S - m_ref), pack to bf16 pairs; 4-way partial sums for l
    float ls0 = 0.0f, ls1 = 0.0f, ls2 = 0.0f, ls3 = 0.0f;
    unsigned pk0[4][2], pk1[4][2];
#pragma unroll
    for (int q = 0; q < 4; ++q) {
#pragma unroll
      for (int wi = 0; wi < 2; ++wi) {
        float a0 = __builtin_exp2f(s0[4 * q + 2 * wi] - m_ref);
        float a1 = __builtin_exp2f(s0[4 * q + 2 * wi + 1] - m_ref);
        float b0 = __builtin_exp2f(s1[4 * q + 2 * wi] - m_ref);
        float b1 = __builtin_exp2f(s1[4 * q + 2 * wi + 1] - m_ref);
        ls0 += a0; ls1 += a1; ls2 += b0; ls3 += b1;
        pk0[q][wi] = pack2(a0, a1);
        pk1[q][wi] = pack2(b0, b1);
      }
    }
    float lsum = (ls0 + ls1) + (ls2 + ls3);
    lsum += __shfl_xor(lsum, 32);
    l_run += lsum;

    // in-register transpose: S-frag (rows 4-interleaved) -> PV B-frag (rows 8-contig).
    bf16x8 pf[4];
#pragma unroll
    for (int kk = 0; kk < 4; ++kk) {
      const int qb = 2 * (kk & 1);
      union { unsigned u[4]; bf16x8 v; } pu;
#pragma unroll
      for (int wi = 0; wi < 2; ++wi) {
        unsigned a  = (kk < 2) ? pk0[qb][wi]     : pk1[qb][wi];
        unsigned bv = (kk < 2) ? pk0[qb + 1][wi] : pk1[qb + 1][wi];
        unsigned sv = h ? a : bv;
        unsigned rv = (unsigned)__shfl_xor((int)sv, 32);
        pu.u[wi]     = h ? rv : a;
        pu.u[2 + wi] = h ? bv : rv;
      }
      pf[kk] = pu.v;
    }

    // O[c,j] += V[c,i] * P[i,j]
#pragma unroll
    for (int ct = 0; ct < 8; ++ct) {
      const bf16* vrow = vb + ct * 2048;
      oacc[ct] = mfma32(*(const bf16x8*)(vrow + voff[0]), pf[0], oacc[ct]);
      oacc[ct] = mfma32(*(const bf16x8*)(vrow + voff[1]), pf[1], oacc[ct]);
      oacc[ct] = mfma32(*(const bf16x8*)(vrow + voff[2]), pf[2], oacc[ct]);
      oacc[ct] = mfma32(*(const bf16x8*)(vrow + voff[3]), pf[3], oacc[ct]);
    }

    asm volatile("s_waitcnt vmcnt(0)" ::: "memory");
    __syncthreads();
  }

  // ---- in-block merge of the two key-half partials ----
  // obuf: f32 [128 j][260 padded c] over the dead V buffers (b128, octet-conflict-free)
  float* obuf = (float*)smem;
  const int jl = wg * 32 + ln31;
  if (g == 1) {
#pragma unroll
    for (int ct = 0; ct < 8; ++ct)
#pragma unroll
      for (int q = 0; q < 4; ++q) {
        f32x4 v;
        v[0] = oacc[ct][4 * q + 0];
        v[1] = oacc[ct][4 * q + 1];
        v[2] = oacc[ct][4 * q + 2];
        v[3] = oacc[ct][4 * q + 3];
        *(f32x4*)&obuf[jl * 260 + ct * 32 + 8 * q + 4 * h] = v;
      }
    if (h == 0) { msh[jl] = m_ref; lsh[jl] = l_run; }
  }
  __syncthreads();
  if (g == 0) {
    const float mB = msh[jl], lB = lsh[jl];
    const float mN = fmaxf(m_ref, mB);
    const float eA = __builtin_exp2f(m_ref - mN);
    const float eB = __builtin_exp2f(mB - mN);
    const float l = l_run * eA + lB * eB;
    const float ginv = gammap[0] / l;
    const float* xb = x + (size_t)b * CC * NN;
    float* ob = out + (size_t)b * CC * NN;
#pragma unroll
    for (int ct = 0; ct < 8; ++ct)
#pragma unroll
      for (int q = 0; q < 4; ++q) {
        f32x4 vB = *(const f32x4*)&obuf[jl * 260 + ct * 32 + 8 * q + 4 * h];
#pragma unroll
        for (int s = 0; s < 4; ++s) {
          int c = ct * 32 + 8 * q + 4 * h + s;
          size_t idx = (size_t)c * NN + j;
          float val = oacc[ct][4 * q + s] * eA + vB[s] * eB;
          ob[idx] = fmaf(ginv, val, xb[idx]);
        }
      }
  }
}

extern "C" void kernel_launch(void* const* d_in, const int* in_sizes, int n_in,
                              void* d_out, int out_size, void* d_ws, size_t ws_size,
                              hipStream_t stream) {
  const float* x     = (const float*)d_in[0];
  const float* Wf    = (const float*)d_in[1];
  const float* bfv   = (const float*)d_in[2];
  const float* Wg    = (const float*)d_in[3];
  const float* bg    = (const float*)d_in[4];
  const float* Wh    = (const float*)d_in[5];
  const float* bh    = (const float*)d_in[6];
  const float* gamma = (const float*)d_in[7];
  float* out = (float*)d_out;

  // workspace layout (~21.2 MB); xT lives in d_out (33.5 MB) since out is written last.
  char* ws = (char*)d_ws;
  bf16* fxT  = (bf16*)(ws);                      //  2 MB
  bf16* gxT  = (bf16*)(ws + 2097152);            //  2 MB
  bf16* hx   = (bf16*)(ws + 4194304);            // 16.8 MB
  bf16* Wcat = (bf16*)(ws + 20971520);           // 160 KB
  float* bcat = (float*)(ws + 21135360);         // 1.25 KB
  bf16* xT = (bf16*)d_out;                       // 16.8 MB scratch, dead before k_attn writes

  k_transpose<<<dim3(64, 4, 8), 256, 0, stream>>>(x, xT);
  k_wprep<<<dim3(320), 64, 0, stream>>>(Wf, bfv, Wg, bg, Wh, bh, Wcat, bcat);
  k_proj<<<dim3(256), 256, 0, stream>>>(xT, Wcat, bcat, fxT, gxT, hx);
  k_attn<<<dim3(256), 512, 133120, stream>>>(fxT, gxT, hx, x, gamma, out);
}

// Round 4
// 158.525 us; speedup vs baseline: 1.3015x; 1.0204x over previous
//
#include <hip/hip_runtime.h>
#include <stdint.h>

// SAGAN self-attention, MI355X gfx950.
// B=8, C=256, CK=32, N=4096. fp32 in/out, bf16 MFMA internally.

typedef __bf16 bf16;
typedef __bf16 bf16x8 __attribute__((ext_vector_type(8)));
typedef float  f32x16 __attribute__((ext_vector_type(16)));
typedef float  f32x4  __attribute__((ext_vector_type(4)));

#define BATCH 8
#define CC    256
#define CKK   32
#define NN    4096
#define LOG2E 1.4426950408889634f

__device__ __forceinline__ f32x16 zero16() {
  f32x16 z;
#pragma unroll
  for (int i = 0; i < 16; ++i) z[i] = 0.0f;
  return z;
}

__device__ __forceinline__ unsigned pack2(float lo, float hi) {
  unsigned short a = __builtin_bit_cast(unsigned short, (bf16)lo);
  unsigned short b = __builtin_bit_cast(unsigned short, (bf16)hi);
  return (unsigned)a | ((unsigned)b << 16);
}

__device__ __forceinline__ f32x16 mfma32(bf16x8 a, bf16x8 b, f32x16 c) {
  return __builtin_amdgcn_mfma_f32_32x32x16_bf16(a, b, c, 0, 0, 0);
}

#define GLDS16(srcp, dstp)                                                         \
  __builtin_amdgcn_global_load_lds(                                               \
      (const __attribute__((address_space(1))) void*)(srcp),                      \
      (__attribute__((address_space(3))) void*)(dstp), 16, 0, 0)

// ---------------- kernel 0a: x f32 [B][C][N] -> xT bf16 [B][N][C] ----------------
__global__ __launch_bounds__(256) void k_transpose(const float* __restrict__ x,
                                                   bf16* __restrict__ xT) {
  __shared__ float tile[64][65];
  const int n0 = blockIdx.x * 64;
  const int c0 = blockIdx.y * 64;
  const int b  = blockIdx.z;
  const int t = threadIdx.x;
  const int tn = t & 63, trow = t >> 6;
#pragma unroll
  for (int i = 0; i < 16; ++i) {
    int c = trow + i * 4;
    tile[c][tn] = x[((size_t)(b * CC + c0 + c)) * NN + n0 + tn];
  }
  __syncthreads();
#pragma unroll
  for (int i = 0; i < 16; ++i) {
    int n = trow + i * 4;
    xT[((size_t)(b * NN + n0 + n)) * CC + c0 + tn] = (bf16)tile[tn][n];
  }
}

// ---------------- kernel 0b: weight pack ----------------
// Wcat bf16 [320][256]: rows 0..31 = Wf, 32..63 = Wg*log2e, 64..319 = Wh.
__global__ __launch_bounds__(64) void k_wprep(const float* __restrict__ Wf, const float* __restrict__ bfv,
                                              const float* __restrict__ Wg, const float* __restrict__ bg,
                                              const float* __restrict__ Wh, const float* __restrict__ bh,
                                              bf16* __restrict__ Wcat, float* __restrict__ bcat) {
  const int ko = blockIdx.x;  // 0..319
  const int t = threadIdx.x;
  const float* src;
  float scale = 1.0f;
  if (ko < 32) src = Wf + (size_t)ko * CC;
  else if (ko < 64) { src = Wg + (size_t)(ko - 32) * CC; scale = LOG2E; }
  else src = Wh + (size_t)(ko - 64) * CC;
#pragma unroll
  for (int i = 0; i < 4; ++i)
    Wcat[(size_t)ko * CC + t + i * 64] = (bf16)(src[t + i * 64] * scale);
  if (ko == 0) {
    for (int i = t; i < 320; i += 64) {
      float v = (i < 32) ? bfv[i] : (i < 64) ? bg[i - 32] * LOG2E : bh[i - 64];
      bcat[i] = v;
    }
  }
}

// ---------------- kernel 1: projections (MFMA GEMM 320x256 @ x) ----------------
__global__ __launch_bounds__(256, 1) void k_proj(const bf16* __restrict__ xT,
                                                 const bf16* __restrict__ Wcat,
                                                 const float* __restrict__ bcat,
                                                 bf16* __restrict__ fxT, bf16* __restrict__ gxT,
                                                 bf16* __restrict__ hx) {
  const int d = blockIdx.x;
  const int b = d & 7, nb = d >> 3;          // batch -> XCD alignment
  const int t = threadIdx.x;
  const int w = t >> 6, ln = t & 63, ln31 = ln & 31, h = ln >> 5;
  const int n = nb * 128 + w * 32 + ln31;    // this lane's output column

  f32x16 acc[10];
#pragma unroll
  for (int mt = 0; mt < 10; ++mt) acc[mt] = zero16();

  const bf16* xrow = xT + ((size_t)(b * NN + n)) * CC;
#pragma unroll
  for (int ks = 0; ks < 16; ++ks) {
    bf16x8 bfrag = *(const bf16x8*)(xrow + ks * 16 + h * 8);  // B[k=c][n]
#pragma unroll
    for (int mt = 0; mt < 10; ++mt) {
      bf16x8 afrag = *(const bf16x8*)(Wcat + (size_t)(mt * 32 + ln31) * CC + ks * 16 + h * 8);
      acc[mt] = mfma32(afrag, bfrag, acc[mt]);
    }
  }

#pragma unroll
  for (int mt = 0; mt < 10; ++mt) {
#pragma unroll
    for (int q = 0; q < 4; ++q) {
      const int ko0 = mt * 32 + 8 * q + 4 * h;  // rows ko0..ko0+3
      float v0 = acc[mt][4 * q + 0] + bcat[ko0 + 0];
      float v1 = acc[mt][4 * q + 1] + bcat[ko0 + 1];
      float v2 = acc[mt][4 * q + 2] + bcat[ko0 + 2];
      float v3 = acc[mt][4 * q + 3] + bcat[ko0 + 3];
      if (mt < 2) {
        bf16* dst = (mt == 0 ? fxT : gxT) + ((size_t)(b * NN + n)) * CKK + (8 * q + 4 * h);
        uint2 pv;
        pv.x = pack2(v0, v1);
        pv.y = pack2(v2, v3);
        *(uint2*)dst = pv;
      } else {
        const int c = ko0 - 64;
        hx[((size_t)(b * CC + c + 0)) * NN + n] = (bf16)v0;
        hx[((size_t)(b * CC + c + 1)) * NN + n] = (bf16)v1;
        hx[((size_t)(b * CC + c + 2)) * NN + n] = (bf16)v2;
        hx[((size_t)(b * CC + c + 3)) * NN + n] = (bf16)v3;
      }
    }
  }
}

// ---------------- kernel 2: flash attention, counted-vmcnt 4-deep pipeline ----------------
// Grid 256 (b = blk&7 -> XCD-local V/K). 512 thr = 2 key-groups x 4 waves.
// KVBLK=32. Per group: 4-buffer ring of {V 16KB chunk-permuted + K 2KB} tiles,
// staged via global_load_lds (5 per wave per tile, uniform). Loop never drains:
// s_waitcnt vmcnt(10) -> raw s_barrier -> issue stage(t+3) -> compute(t).
// Physical layout: cell (row, chunk16B c) at slot row*4 + (c ^ ((row>>1)&3)):
// every 8-lane group of a ds_read_b128 hits 8 distinct bank quads (conflict-free),
// staging source stays 64B-coalesced.
__global__ __launch_bounds__(512, 2) void k_attn(const bf16* __restrict__ fxT,
                                                 const bf16* __restrict__ gxT,
                                                 const bf16* __restrict__ hx,
                                                 const float* __restrict__ x,
                                                 const float* __restrict__ gammap,
                                                 float* __restrict__ out) {
  extern __shared__ __align__(16) char smem[];   // 147456: V 2x4x16KB | K 2x4x2KB
  __shared__ float msh[128], lsh[128];
  const int d = blockIdx.x;
  const int b = d & 7, jb = d >> 3;
  const int t = threadIdx.x;
  const int g = t >> 8;                 // key-half group (waves 0-3 / 4-7)
  const int tg = t & 255;
  const int wg = tg >> 6;               // wave-in-group
  const int ln = t & 63, ln31 = ln & 31, h = ln >> 5;
  const int j = jb * 128 + wg * 32 + ln31;
  const int kbase = g * 2048;

  const bf16* fxb = fxT + (size_t)b * NN * CKK;
  const bf16* hxb = hx + (size_t)b * CC * NN;

  bf16* vsg = (bf16*)smem + g * 32768;            // 4 bufs x 8192 elems
  bf16* ksg = (bf16*)(smem + 131072) + g * 4096;  // 4 bufs x 1024 elems

  const bf16* qrow = gxT + ((size_t)b * NN + j) * CKK;
  bf16x8 qf0 = *(const bf16x8*)(qrow + h * 8);        // ck 0..15 (h-half)
  bf16x8 qf1 = *(const bf16x8*)(qrow + 16 + h * 8);   // ck 16..31

  // per-lane tile read offsets (elements): row=ln31, phys chunk = (2ks+h) ^ tau
  const int tau = (ln31 >> 1) & 3;
  const int koff0 = ln31 * 32 + ((h ^ tau) * 8);        // ks=0 -> kc = h
  const int koff1 = ln31 * 32 + (((2 + h) ^ tau) * 8);  // ks=1 -> kc = 2+h

  // staging source per-lane pieces: instr covers 64 slots; lane l -> slot base+l
  const int lq = ln >> 2, lr = ln & 3;
  const int icv = lr ^ ((lq >> 1) & 3);  // logical chunk stored at this lane's slot

#define STAGE(vdst, kdst, i0s)                                                        \
  {                                                                                    \
    _Pragma("unroll")                                                                  \
    for (int q = 0; q < 4; ++q) {                                                      \
      const bf16* vsrc = hxb + (size_t)((wg * 4 + q) * 16 + lq) * NN + (i0s) + icv * 8; \
      GLDS16(vsrc, (vdst) + (wg * 4 + q) * 512);                                       \
    }                                                                                  \
    const bf16* ksrc = fxb + (size_t)((i0s) + (wg & 1) * 16 + lq) * CKK + icv * 8;     \
    GLDS16(ksrc, (kdst) + (wg & 1) * 512);                                             \
  }

  f32x16 oacc[8];
#pragma unroll
  for (int ct = 0; ct < 8; ++ct) oacc[ct] = zero16();
  float m_ref = -__builtin_inff();
  float l_run = 0.0f;

  // prologue: stage tiles 0..2 (15 loads outstanding per wave)
#pragma unroll
  for (int tt = 0; tt < 3; ++tt)
    STAGE(vsg + tt * 8192, ksg + tt * 1024, kbase + tt * 32);

  for (int kb = 0; kb < 64; ++kb) {
    // tile kb's 5 loads are the oldest; 10 newer (tiles kb+1, kb+2) may stay in flight
    asm volatile("s_waitcnt vmcnt(10)" ::: "memory");
    __builtin_amdgcn_s_barrier();
    asm volatile("" ::: "memory");

    {  // issue stage(t+3) (wraps at the tail: data valid but unused)
      const int tt = (kb + 3) & 63;
      const int bu = (kb + 3) & 3;
      STAGE(vsg + bu * 8192, ksg + bu * 1024, kbase + tt * 32);
    }

    const bf16* vb = vsg + (kb & 3) * 8192;
    const bf16* kt = ksg + (kb & 3) * 1024;

    bf16x8 kf0 = *(const bf16x8*)(kt + koff0);
    bf16x8 kf1 = *(const bf16x8*)(kt + koff1);

    // S[i,j] over 32 keys (log2 domain via pre-scaled Wg)
    f32x16 s0 = zero16();
    s0 = mfma32(kf0, qf0, s0);
    s0 = mfma32(kf1, qf1, s0);

    // block max over 32 keys for this j — tree + cross-half shfl
    float tm[8];
#pragma unroll
    for (int r = 0; r < 8; ++r) tm[r] = fmaxf(s0[r], s0[r + 8]);
#pragma unroll
    for (int st = 4; st > 0; st >>= 1)
#pragma unroll
      for (int r = 0; r < 4; ++r)
        if (r < st) tm[r] = fmaxf(tm[r], tm[r + st]);
    float smax = fmaxf(tm[0], __shfl_xor(tm[0], 32));

    // defer-max rescale (THR=8 in exp2 domain -> P <= 256, bf16-safe)
    bool need = smax > m_ref + 8.0f;
    if (__any(need)) {
      float rr = need ? __builtin_exp2f(m_ref - smax) : 1.0f;
      if (need) m_ref = smax;
      l_run *= rr;
#pragma unroll
      for (int ct = 0; ct < 8; ++ct)
#pragma unroll
        for (int r = 0; r < 16; ++r) oacc[ct][r] *= rr;
    }

    // P = exp2(S - m_ref), pack bf16 pairs; 2-way partial sums
    float ls0 = 0.0f, ls1 = 0.0f;
    unsigned pk[4][2];
#pragma unroll
    for (int q = 0; q < 4; ++q)
#pragma unroll
      for (int wi = 0; wi < 2; ++wi) {
        float a0 = __builtin_exp2f(s0[4 * q + 2 * wi] - m_ref);
        float a1 = __builtin_exp2f(s0[4 * q + 2 * wi + 1] - m_ref);
        ls0 += a0; ls1 += a1;
        pk[q][wi] = pack2(a0, a1);
      }
    float lsum = ls0 + ls1;
    lsum += __shfl_xor(lsum, 32);
    l_run += lsum;

    // in-register transpose S-frag -> PV B-frags (lane<->lane^32 only)
    bf16x8 pf[2];
#pragma unroll
    for (int ks = 0; ks < 2; ++ks) {
      union { unsigned u[4]; bf16x8 v; } pu;
#pragma unroll
      for (int wi = 0; wi < 2; ++wi) {
        unsigned keep = h ? pk[2 * ks + 1][wi] : pk[2 * ks][wi];
        unsigned send = h ? pk[2 * ks][wi]     : pk[2 * ks + 1][wi];
        unsigned recv = (unsigned)__shfl_xor((int)send, 32);
        pu.u[wi]     = h ? recv : keep;
        pu.u[2 + wi] = h ? keep : recv;
      }
      pf[ks] = pu.v;
    }

    // O[c,j] += V[c,i] * P[i,j]
    __builtin_amdgcn_s_setprio(1);
#pragma unroll
    for (int ct = 0; ct < 8; ++ct) {
      const bf16* vrow = vb + ct * 1024;
      oacc[ct] = mfma32(*(const bf16x8*)(vrow + koff0), pf[0], oacc[ct]);
      oacc[ct] = mfma32(*(const bf16x8*)(vrow + koff1), pf[1], oacc[ct]);
    }
    __builtin_amdgcn_s_setprio(0);
  }

  // ---- in-block merge of the two key-half partials ----
  asm volatile("s_waitcnt vmcnt(0) lgkmcnt(0)" ::: "memory");
  __builtin_amdgcn_s_barrier();
  asm volatile("" ::: "memory");

  // obuf: f32 [128 j][260 padded c] over the dead tile buffers
  float* obuf = (float*)smem;
  const int jl = wg * 32 + ln31;
  if (g == 1) {
#pragma unroll
    for (int ct = 0; ct < 8; ++ct)
#pragma unroll
      for (int q = 0; q < 4; ++q) {
        f32x4 v;
        v[0] = oacc[ct][4 * q + 0];
        v[1] = oacc[ct][4 * q + 1];
        v[2] = oacc[ct][4 * q + 2];
        v[3] = oacc[ct][4 * q + 3];
        *(f32x4*)&obuf[jl * 260 + ct * 32 + 8 * q + 4 * h] = v;
      }
    if (h == 0) { msh[jl] = m_ref; lsh[jl] = l_run; }
  }
  __syncthreads();
  if (g == 0) {
    const float mB = msh[jl], lB = lsh[jl];
    const float mN = fmaxf(m_ref, mB);
    const float eA = __builtin_exp2f(m_ref - mN);
    const float eB = __builtin_exp2f(mB - mN);
    const float l = l_run * eA + lB * eB;
    const float ginv = gammap[0] / l;
    const float* xb = x + (size_t)b * CC * NN;
    float* ob = out + (size_t)b * CC * NN;
#pragma unroll
    for (int ct = 0; ct < 8; ++ct)
#pragma unroll
      for (int q = 0; q < 4; ++q) {
        f32x4 vB = *(const f32x4*)&obuf[jl * 260 + ct * 32 + 8 * q + 4 * h];
#pragma unroll
        for (int s = 0; s < 4; ++s) {
          int c = ct * 32 + 8 * q + 4 * h + s;
          size_t idx = (size_t)c * NN + j;
          float val = oacc[ct][4 * q + s] * eA + vB[s] * eB;
          ob[idx] = fmaf(ginv, val, xb[idx]);
        }
      }
  }
#undef STAGE
}

extern "C" void kernel_launch(void* const* d_in, const int* in_sizes, int n_in,
                              void* d_out, int out_size, void* d_ws, size_t ws_size,
                              hipStream_t stream) {
  const float* x     = (const float*)d_in[0];
  const float* Wf    = (const float*)d_in[1];
  const float* bfv   = (const float*)d_in[2];
  const float* Wg    = (const float*)d_in[3];
  const float* bg    = (const float*)d_in[4];
  const float* Wh    = (const float*)d_in[5];
  const float* bh    = (const float*)d_in[6];
  const float* gamma = (const float*)d_in[7];
  float* out = (float*)d_out;

  // workspace layout (~21.2 MB); xT lives in d_out (33.5 MB) since out is written last.
  char* ws = (char*)d_ws;
  bf16* fxT  = (bf16*)(ws);                      //  2 MB
  bf16* gxT  = (bf16*)(ws + 2097152);            //  2 MB
  bf16* hx   = (bf16*)(ws + 4194304);            // 16.8 MB
  bf16* Wcat = (bf16*)(ws + 20971520);           // 160 KB
  float* bcat = (float*)(ws + 21135360);         // 1.25 KB
  bf16* xT = (bf16*)d_out;                       // 16.8 MB scratch, dead before k_attn writes

  k_transpose<<<dim3(64, 4, 8), 256, 0, stream>>>(x, xT);
  k_wprep<<<dim3(320), 64, 0, stream>>>(Wf, bfv, Wg, bg, Wh, bh, Wcat, bcat);
  k_proj<<<dim3(256), 256, 0, stream>>>(xT, Wcat, bcat, fxT, gxT, hx);
  k_attn<<<dim3(256), 512, 147456, stream>>>(fxT, gxT, hx, x, gamma, out);
}

// Round 5
// 155.102 us; speedup vs baseline: 1.3302x; 1.0221x over previous
//
#include <hip/hip_runtime.h>
#include <stdint.h>

// SAGAN self-attention, MI355X gfx950.
// B=8, C=256, CK=32, N=4096. fp32 in/out, bf16 MFMA internally.

typedef __bf16 bf16;
typedef __bf16 bf16x8 __attribute__((ext_vector_type(8)));
typedef float  f32x16 __attribute__((ext_vector_type(16)));
typedef float  f32x4  __attribute__((ext_vector_type(4)));

#define BATCH 8
#define CC    256
#define CKK   32
#define NN    4096
#define LOG2E 1.4426950408889634f

__device__ __forceinline__ f32x16 zero16() {
  f32x16 z;
#pragma unroll
  for (int i = 0; i < 16; ++i) z[i] = 0.0f;
  return z;
}

__device__ __forceinline__ unsigned pack2(float lo, float hi) {
  unsigned short a = __builtin_bit_cast(unsigned short, (bf16)lo);
  unsigned short b = __builtin_bit_cast(unsigned short, (bf16)hi);
  return (unsigned)a | ((unsigned)b << 16);
}

__device__ __forceinline__ f32x16 mfma32(bf16x8 a, bf16x8 b, f32x16 c) {
  return __builtin_amdgcn_mfma_f32_32x32x16_bf16(a, b, c, 0, 0, 0);
}

#define GLDS16(srcp, dstp)                                                         \
  __builtin_amdgcn_global_load_lds(                                               \
      (const __attribute__((address_space(1))) void*)(srcp),                      \
      (__attribute__((address_space(3))) void*)(dstp), 16, 0, 0)

// ---------------- kernel 0a: x f32 [B][C][N] -> xT bf16 [B][N][C] ----------------
__global__ __launch_bounds__(256) void k_transpose(const float* __restrict__ x,
                                                   bf16* __restrict__ xT) {
  __shared__ float tile[64][65];
  const int n0 = blockIdx.x * 64;
  const int c0 = blockIdx.y * 64;
  const int b  = blockIdx.z;
  const int t = threadIdx.x;
  const int tn = t & 63, trow = t >> 6;
#pragma unroll
  for (int i = 0; i < 16; ++i) {
    int c = trow + i * 4;
    tile[c][tn] = x[((size_t)(b * CC + c0 + c)) * NN + n0 + tn];
  }
  __syncthreads();
#pragma unroll
  for (int i = 0; i < 16; ++i) {
    int n = trow + i * 4;
    xT[((size_t)(b * NN + n0 + n)) * CC + c0 + tn] = (bf16)tile[tn][n];
  }
}

// ---------------- kernel 0b: weight pack ----------------
// Wcat bf16 [320][256]: rows 0..31 = Wf, 32..63 = Wg*log2e, 64..319 = Wh.
__global__ __launch_bounds__(64) void k_wprep(const float* __restrict__ Wf, const float* __restrict__ bfv,
                                              const float* __restrict__ Wg, const float* __restrict__ bg,
                                              const float* __restrict__ Wh, const float* __restrict__ bh,
                                              bf16* __restrict__ Wcat, float* __restrict__ bcat) {
  const int ko = blockIdx.x;  // 0..319
  const int t = threadIdx.x;
  const float* src;
  float scale = 1.0f;
  if (ko < 32) src = Wf + (size_t)ko * CC;
  else if (ko < 64) { src = Wg + (size_t)(ko - 32) * CC; scale = LOG2E; }
  else src = Wh + (size_t)(ko - 64) * CC;
#pragma unroll
  for (int i = 0; i < 4; ++i)
    Wcat[(size_t)ko * CC + t + i * 64] = (bf16)(src[t + i * 64] * scale);
  if (ko == 0) {
    for (int i = t; i < 320; i += 64) {
      float v = (i < 32) ? bfv[i] : (i < 64) ? bg[i - 32] * LOG2E : bh[i - 64];
      bcat[i] = v;
    }
  }
}

// ---------------- kernel 1: projections (MFMA GEMM 320x256 @ x) ----------------
__global__ __launch_bounds__(256, 1) void k_proj(const bf16* __restrict__ xT,
                                                 const bf16* __restrict__ Wcat,
                                                 const float* __restrict__ bcat,
                                                 bf16* __restrict__ fxT, bf16* __restrict__ gxT,
                                                 bf16* __restrict__ hx) {
  const int d = blockIdx.x;
  const int b = d & 7, nb = d >> 3;          // batch -> XCD alignment
  const int t = threadIdx.x;
  const int w = t >> 6, ln = t & 63, ln31 = ln & 31, h = ln >> 5;
  const int n = nb * 128 + w * 32 + ln31;    // this lane's output column

  f32x16 acc[10];
#pragma unroll
  for (int mt = 0; mt < 10; ++mt) acc[mt] = zero16();

  const bf16* xrow = xT + ((size_t)(b * NN + n)) * CC;
#pragma unroll
  for (int ks = 0; ks < 16; ++ks) {
    bf16x8 bfrag = *(const bf16x8*)(xrow + ks * 16 + h * 8);  // B[k=c][n]
#pragma unroll
    for (int mt = 0; mt < 10; ++mt) {
      bf16x8 afrag = *(const bf16x8*)(Wcat + (size_t)(mt * 32 + ln31) * CC + ks * 16 + h * 8);
      acc[mt] = mfma32(afrag, bfrag, acc[mt]);
    }
  }

#pragma unroll
  for (int mt = 0; mt < 10; ++mt) {
#pragma unroll
    for (int q = 0; q < 4; ++q) {
      const int ko0 = mt * 32 + 8 * q + 4 * h;  // rows ko0..ko0+3
      float v0 = acc[mt][4 * q + 0] + bcat[ko0 + 0];
      float v1 = acc[mt][4 * q + 1] + bcat[ko0 + 1];
      float v2 = acc[mt][4 * q + 2] + bcat[ko0 + 2];
      float v3 = acc[mt][4 * q + 3] + bcat[ko0 + 3];
      if (mt < 2) {
        bf16* dst = (mt == 0 ? fxT : gxT) + ((size_t)(b * NN + n)) * CKK + (8 * q + 4 * h);
        uint2 pv;
        pv.x = pack2(v0, v1);
        pv.y = pack2(v2, v3);
        *(uint2*)dst = pv;
      } else {
        const int c = ko0 - 64;
        hx[((size_t)(b * CC + c + 0)) * NN + n] = (bf16)v0;
        hx[((size_t)(b * CC + c + 1)) * NN + n] = (bf16)v1;
        hx[((size_t)(b * CC + c + 2)) * NN + n] = (bf16)v2;
        hx[((size_t)(b * CC + c + 3)) * NN + n] = (bf16)v3;
      }
    }
  }
}

// ---------------- kernel 2: flash attention, KVBLK=64, counted-vmcnt ring-2 ----------------
// Grid 256 (b = blk&7 -> XCD-local V/K). 512 thr = 2 key-groups x 4 waves.
// Per group: ring-2 of {V 32KB [256 c][64 i] + K 4KB [64 i][32 ck]} tiles; 9
// global_load_lds per wave per tile (8 V + 1 K), uniform. Loop never drains:
// s_waitcnt vmcnt(9) -> raw s_barrier -> issue stage(t+1) -> compute(t).
// V layout: 128B rows (c), 16B chunk at phys p holds logical p ^ (c&7) (m214
// pattern); K rows 64B, phys p holds logical p ^ ((i>>1)&3).
__global__ __launch_bounds__(512, 2) void k_attn(const bf16* __restrict__ fxT,
                                                 const bf16* __restrict__ gxT,
                                                 const bf16* __restrict__ hx,
                                                 const float* __restrict__ x,
                                                 const float* __restrict__ gammap,
                                                 float* __restrict__ out) {
  extern __shared__ __align__(16) char smem[];   // 147456: V 2g x 2buf x 32KB | K 2g x 2buf x 4KB
  __shared__ float msh[128], lsh[128];
  const int d = blockIdx.x;
  const int b = d & 7, jb = d >> 3;
  const int t = threadIdx.x;
  const int g = t >> 8;                 // key-half group (waves 0-3 / 4-7)
  const int tg = t & 255;
  const int wg = tg >> 6;               // wave-in-group
  const int ln = t & 63, ln31 = ln & 31, h = ln >> 5;
  const int j = jb * 128 + wg * 32 + ln31;
  const int kbase = g * 2048;

  const bf16* fxb = fxT + (size_t)b * NN * CKK;
  const bf16* hxb = hx + (size_t)b * CC * NN;

  bf16* vsg = (bf16*)smem + g * 32768;            // 2 bufs x 16384 elems
  bf16* ksg = (bf16*)(smem + 131072) + g * 4096;  // 2 bufs x 2048 elems

  const bf16* qrow = gxT + ((size_t)b * NN + j) * CKK;
  bf16x8 qf0 = *(const bf16x8*)(qrow + h * 8);        // ck 0..15 (h-half)
  bf16x8 qf1 = *(const bf16x8*)(qrow + 16 + h * 8);   // ck 16..31

  // V read offsets: row c=ln31 (+ct*32), logical chunk 2kk+h, phys = logical^(c&7)
  int voff[4];
#pragma unroll
  for (int kk = 0; kk < 4; ++kk)
    voff[kk] = ln31 * 64 + (((2 * kk + h) ^ (ln31 & 7)) * 8);
  // K read offsets: row i=ln31/ln31+32, logical chunk h / 2+h, phys = logical^((i>>1)&3)
  const int tk = (ln31 >> 1) & 3;
  const int koff00 = ln31 * 32 + ((h ^ tk) * 8);
  const int koff01 = ln31 * 32 + (((2 + h) ^ tk) * 8);

  // staging per-lane pieces
  const int lq8 = ln >> 3, lr8 = ln & 7;          // V: 8 rows x 8 chunks per GLDS
  const int icv8 = lr8 ^ lq8;                     // logical chunk at phys slot lr8
  const int lq4 = ln >> 2, lr4 = ln & 3;          // K: 16 rows x 4 chunks per GLDS
  const int icv4 = lr4 ^ ((lq4 >> 1) & 3);

#define STAGE(vdst, kdst, i0s)                                                          \
  {                                                                                      \
    _Pragma("unroll")                                                                    \
    for (int q = 0; q < 8; ++q) {                                                        \
      const bf16* vsrc = hxb + (size_t)((wg * 8 + q) * 8 + lq8) * NN + (i0s) + icv8 * 8; \
      GLDS16(vsrc, (vdst) + (wg * 8 + q) * 512);                                         \
    }                                                                                    \
    const bf16* ksrc = fxb + (size_t)((i0s) + wg * 16 + lq4) * CKK + icv4 * 8;           \
    GLDS16(ksrc, (kdst) + wg * 512);                                                     \
  }

  f32x16 oacc[8];
#pragma unroll
  for (int ct = 0; ct < 8; ++ct) oacc[ct] = zero16();
  float m_ref = -__builtin_inff();
  float l_run = 0.0f;

  // prologue: stage tiles 0,1 (18 loads outstanding per wave)
#pragma unroll
  for (int tt = 0; tt < 2; ++tt)
    STAGE(vsg + tt * 16384, ksg + tt * 2048, kbase + tt * 64);

  for (int kb = 0; kb < 32; ++kb) {
    // tile kb's 9 loads are the oldest; tile kb+1's 9 stay in flight
    asm volatile("s_waitcnt vmcnt(9)" ::: "memory");
    __builtin_amdgcn_s_barrier();
    asm volatile("" ::: "memory");

    {  // issue stage(t+1) into the other buffer (wraps at tail: dead data)
      const int tt = (kb + 1) & 31;
      const int bu = (kb + 1) & 1;
      STAGE(vsg + bu * 16384, ksg + bu * 2048, kbase + tt * 64);
    }

    const bf16* vb = vsg + (kb & 1) * 16384;
    const bf16* kt = ksg + (kb & 1) * 2048;

    bf16x8 kf00 = *(const bf16x8*)(kt + koff00);
    bf16x8 kf01 = *(const bf16x8*)(kt + koff01);
    bf16x8 kf10 = *(const bf16x8*)(kt + 1024 + koff00);
    bf16x8 kf11 = *(const bf16x8*)(kt + 1024 + koff01);

    // S[i,j] over 64 keys (log2 domain via pre-scaled Wg)
    f32x16 s0 = zero16(), s1 = zero16();
    s0 = mfma32(kf00, qf0, s0);
    s0 = mfma32(kf01, qf1, s0);
    s1 = mfma32(kf10, qf0, s1);
    s1 = mfma32(kf11, qf1, s1);

    // block max over 64 keys for this j — tree + cross-half shfl
    float tm[16];
#pragma unroll
    for (int r = 0; r < 16; ++r) tm[r] = fmaxf(s0[r], s1[r]);
#pragma unroll
    for (int st = 8; st > 0; st >>= 1)
#pragma unroll
      for (int r = 0; r < 8; ++r)
        if (r < st) tm[r] = fmaxf(tm[r], tm[r + st]);
    float smax = fmaxf(tm[0], __shfl_xor(tm[0], 32));

    // defer-max rescale (THR=8 in exp2 domain -> P <= 256, bf16-safe)
    bool need = smax > m_ref + 8.0f;
    if (__any(need)) {
      float rr = need ? __builtin_exp2f(m_ref - smax) : 1.0f;
      if (need) m_ref = smax;
      l_run *= rr;
#pragma unroll
      for (int ct = 0; ct < 8; ++ct)
#pragma unroll
        for (int r = 0; r < 16; ++r) oacc[ct][r] *= rr;
    }

    // P = exp2(S - m_ref), pack bf16 pairs; 4-way partial sums
    float ls0 = 0.0f, ls1 = 0.0f, ls2 = 0.0f, ls3 = 0.0f;
    unsigned pk0[4][2], pk1[4][2];
#pragma unroll
    for (int q = 0; q < 4; ++q) {
#pragma unroll
      for (int wi = 0; wi < 2; ++wi) {
        float a0 = __builtin_exp2f(s0[4 * q + 2 * wi] - m_ref);
        float a1 = __builtin_exp2f(s0[4 * q + 2 * wi + 1] - m_ref);
        float b0 = __builtin_exp2f(s1[4 * q + 2 * wi] - m_ref);
        float b1 = __builtin_exp2f(s1[4 * q + 2 * wi + 1] - m_ref);
        ls0 += a0; ls1 += a1; ls2 += b0; ls3 += b1;
        pk0[q][wi] = pack2(a0, a1);
        pk1[q][wi] = pack2(b0, b1);
      }
    }
    float lsum = (ls0 + ls1) + (ls2 + ls3);
    lsum += __shfl_xor(lsum, 32);
    l_run += lsum;

    // in-register transpose: S-frag (rows 4-interleaved) -> PV B-frag (rows 8-contig)
    bf16x8 pf[4];
#pragma unroll
    for (int kk = 0; kk < 4; ++kk) {
      const int qb = 2 * (kk & 1);
      union { unsigned u[4]; bf16x8 v; } pu;
#pragma unroll
      for (int wi = 0; wi < 2; ++wi) {
        unsigned a  = (kk < 2) ? pk0[qb][wi]     : pk1[qb][wi];
        unsigned bv = (kk < 2) ? pk0[qb + 1][wi] : pk1[qb + 1][wi];
        unsigned sv = h ? a : bv;
        unsigned rv = (unsigned)__shfl_xor((int)sv, 32);
        pu.u[wi]     = h ? rv : a;
        pu.u[2 + wi] = h ? bv : rv;
      }
      pf[kk] = pu.v;
    }

    // O[c,j] += V[c,i] * P[i,j]
    __builtin_amdgcn_s_setprio(1);
#pragma unroll
    for (int ct = 0; ct < 8; ++ct) {
      const bf16* vrow = vb + ct * 2048;
      oacc[ct] = mfma32(*(const bf16x8*)(vrow + voff[0]), pf[0], oacc[ct]);
      oacc[ct] = mfma32(*(const bf16x8*)(vrow + voff[1]), pf[1], oacc[ct]);
      oacc[ct] = mfma32(*(const bf16x8*)(vrow + voff[2]), pf[2], oacc[ct]);
      oacc[ct] = mfma32(*(const bf16x8*)(vrow + voff[3]), pf[3], oacc[ct]);
    }
    __builtin_amdgcn_s_setprio(0);
  }

  // ---- in-block merge of the two key-half partials ----
  asm volatile("s_waitcnt vmcnt(0) lgkmcnt(0)" ::: "memory");
  __builtin_amdgcn_s_barrier();
  asm volatile("" ::: "memory");

  // obuf: f32 [128 j][260 padded c] over the dead tile buffers
  float* obuf = (float*)smem;
  const int jl = wg * 32 + ln31;
  if (g == 1) {
#pragma unroll
    for (int ct = 0; ct < 8; ++ct)
#pragma unroll
      for (int q = 0; q < 4; ++q) {
        f32x4 v;
        v[0] = oacc[ct][4 * q + 0];
        v[1] = oacc[ct][4 * q + 1];
        v[2] = oacc[ct][4 * q + 2];
        v[3] = oacc[ct][4 * q + 3];
        *(f32x4*)&obuf[jl * 260 + ct * 32 + 8 * q + 4 * h] = v;
      }
    if (h == 0) { msh[jl] = m_ref; lsh[jl] = l_run; }
  }
  __syncthreads();
  if (g == 0) {
    const float mB = msh[jl], lB = lsh[jl];
    const float mN = fmaxf(m_ref, mB);
    const float eA = __builtin_exp2f(m_ref - mN);
    const float eB = __builtin_exp2f(mB - mN);
    const float l = l_run * eA + lB * eB;
    const float ginv = gammap[0] / l;
    const float* xb = x + (size_t)b * CC * NN;
    float* ob = out + (size_t)b * CC * NN;
#pragma unroll
    for (int ct = 0; ct < 8; ++ct)
#pragma unroll
      for (int q = 0; q < 4; ++q) {
        f32x4 vB = *(const f32x4*)&obuf[jl * 260 + ct * 32 + 8 * q + 4 * h];
#pragma unroll
        for (int s = 0; s < 4; ++s) {
          int c = ct * 32 + 8 * q + 4 * h + s;
          size_t idx = (size_t)c * NN + j;
          float val = oacc[ct][4 * q + s] * eA + vB[s] * eB;
          ob[idx] = fmaf(ginv, val, xb[idx]);
        }
      }
  }
#undef STAGE
}

extern "C" void kernel_launch(void* const* d_in, const int* in_sizes, int n_in,
                              void* d_out, int out_size, void* d_ws, size_t ws_size,
                              hipStream_t stream) {
  const float* x     = (const float*)d_in[0];
  const float* Wf    = (const float*)d_in[1];
  const float* bfv   = (const float*)d_in[2];
  const float* Wg    = (const float*)d_in[3];
  const float* bg    = (const float*)d_in[4];
  const float* Wh    = (const float*)d_in[5];
  const float* bh    = (const float*)d_in[6];
  const float* gamma = (const float*)d_in[7];
  float* out = (float*)d_out;

  // workspace layout (~21.2 MB); xT lives in d_out (33.5 MB) since out is written last.
  char* ws = (char*)d_ws;
  bf16* fxT  = (bf16*)(ws);                      //  2 MB
  bf16* gxT  = (bf16*)(ws + 2097152);            //  2 MB
  bf16* hx   = (bf16*)(ws + 4194304);            // 16.8 MB
  bf16* Wcat = (bf16*)(ws + 20971520);           // 160 KB
  float* bcat = (float*)(ws + 21135360);         // 1.25 KB
  bf16* xT = (bf16*)d_out;                       // 16.8 MB scratch, dead before k_attn writes

  k_transpose<<<dim3(64, 4, 8), 256, 0, stream>>>(x, xT);
  k_wprep<<<dim3(320), 64, 0, stream>>>(Wf, bfv, Wg, bg, Wh, bh, Wcat, bcat);
  k_proj<<<dim3(256), 256, 0, stream>>>(xT, Wcat, bcat, fxT, gxT, hx);
  k_attn<<<dim3(256), 512, 147456, stream>>>(fxT, gxT, hx, x, gamma, out);
}